// Round 10
// baseline (996.651 us; speedup 1.0000x reference)
//
#include <hip/hip_runtime.h>
#include <hip/hip_bf16.h>

#define NN 50000
#define EE 1600000
#define ET (EE + NN)   // edges + self loops
#define HEADS 8
#define HID 128
#define INC 512
#define H1C (HEADS * HID)   // 1024
#define OUTC 64
#define NEG_SLOPE 0.2f

typedef unsigned short u16;
typedef unsigned int u32;
typedef unsigned char u8;
typedef __attribute__((ext_vector_type(8))) __bf16 bf16x8;
typedef __attribute__((ext_vector_type(4))) float f32x4;
typedef __attribute__((ext_vector_type(2))) float f32x2;
typedef __attribute__((ext_vector_type(4))) u32 u32x4;

__device__ __forceinline__ float lrelu(float x) { return x > 0.f ? x : NEG_SLOPE * x; }
__device__ __forceinline__ float us2f(u16 u) { return __uint_as_float(((u32)u) << 16); }
__device__ __forceinline__ u16 f2bs(float f) {
    u32 u = __float_as_uint(f);
    u += 0x7fffu + ((u >> 16) & 1u);
    return (u16)(u >> 16);
}

__device__ __forceinline__ void gload_lds16(const void* g, void* lds) {
    __builtin_amdgcn_global_load_lds((const __attribute__((address_space(1))) void*)g,
                                     (__attribute__((address_space(3))) void*)lds, 16, 0, 0);
}

// ---------------- fused: x->bf16 cast  +  degree histogram ----------------
#define CVTX_BLOCKS 25000   // NN*INC/4/256
__global__ __launch_bounds__(256) void cvtx_hist_k(const float* __restrict__ x, u16* __restrict__ xb,
                                                   const int* __restrict__ ei, int* __restrict__ cnt) {
    int b = blockIdx.x;
    if (b < CVTX_BLOCKS) {
        int i = b * 256 + threadIdx.x;
        float4 v = ((const float4*)x)[i];
        ushort4 o; o.x = f2bs(v.x); o.y = f2bs(v.y); o.z = f2bs(v.z); o.w = f2bs(v.w);
        ((ushort4*)xb)[i] = o;
    } else {
        int e = (b - CVTX_BLOCKS) * 256 + threadIdx.x;
        if (e < ET) {
            int d = (e < EE) ? ei[EE + e] : (e - EE);
            atomicAdd(&cnt[d], 1);
        }
    }
}

// ---------------- fused weight transposes (bf16) ----------------
__global__ __launch_bounds__(256) void cvt_w_k(const float* __restrict__ W1, u16* __restrict__ W1t,
                                               const float* __restrict__ W2, u16* __restrict__ W2t) {
    int idx = blockIdx.x * 256 + threadIdx.x;
    if (idx < INC * H1C) {               // W1t[n][k] = W1[k][n], 1024x512
        int n = idx >> 9, k = idx & 511;
        W1t[idx] = f2bs(W1[k * 1024 + n]);
    } else {                             // W2t[n][k] = W2[k][n], 64x1024
        int j = idx - INC * H1C;
        int n = j >> 10, k = j & 1023;
        W2t[j] = f2bs(W2[k * 64 + n]);
    }
}

// ---------------- hierarchical scan ----------------
__global__ __launch_bounds__(256) void scan1_k(const int* __restrict__ cnt,
                                               int* __restrict__ startp, int* __restrict__ bsum) {
    __shared__ int ws[8];
    int tid = threadIdx.x;
    int i = blockIdx.x * 256 + tid;
    int v = (i < NN) ? cnt[i] : 0;
    int lane = tid & 63, w = tid >> 6;
    int x = v;
#pragma unroll
    for (int off = 1; off < 64; off <<= 1) { int t = __shfl_up(x, off); if (lane >= off) x += t; }
    if (lane == 63) ws[w] = x;
    __syncthreads();
    if (tid == 0) { int s = 0; for (int k = 0; k < 4; ++k) { int t = ws[k]; ws[k] = s; s += t; } }
    __syncthreads();
    x += ws[w];
    if (i < NN) startp[i] = x - v;
    if (tid == 255) bsum[blockIdx.x] = x;
}

__global__ __launch_bounds__(256) void scan2_k(const int* __restrict__ bsum,
                                               int* __restrict__ boff, int nb) {
    __shared__ int ws[8];
    int tid = threadIdx.x;
    int v = (tid < nb) ? bsum[tid] : 0;
    int lane = tid & 63, w = tid >> 6;
    int x = v;
#pragma unroll
    for (int off = 1; off < 64; off <<= 1) { int t = __shfl_up(x, off); if (lane >= off) x += t; }
    if (lane == 63) ws[w] = x;
    __syncthreads();
    if (tid == 0) { int s = 0; for (int k = 0; k < 4; ++k) { int t = ws[k]; ws[k] = s; s += t; } }
    __syncthreads();
    x += ws[w];
    if (tid < nb) boff[tid] = x - v;
}

__global__ __launch_bounds__(256) void scan3_k(int* __restrict__ startp, const int* __restrict__ boff) {
    int i = blockIdx.x * 256 + threadIdx.x;
    if (i < NN) startp[i] += boff[blockIdx.x];
}

__global__ __launch_bounds__(256) void scatter_k(const int* __restrict__ ei,
                                                 const int* __restrict__ start,
                                                 int* __restrict__ cursor,
                                                 int* __restrict__ csr_src) {
    int e = blockIdx.x * 256 + threadIdx.x;
    if (e >= ET) return;
    int s, d;
    if (e < EE) { s = ei[e]; d = ei[EE + e]; }
    else        { s = e - EE; d = e - EE; }
    int pos = start[d] + atomicAdd(&cursor[d], 1);
    csr_src[pos] = s;
}

// ---------------- MFMA bf16 GEMM with fused alpha epilogue ----------------
__device__ __forceinline__ void stf(float* p, float v) { *p = v; }
__device__ __forceinline__ void stf(u16* p, float v)   { *p = f2bs(v); }
__device__ __forceinline__ void stf(u8* p, float v) {   // fp8 e4m3 (OCP), RTNE
    u32 pk = __builtin_amdgcn_cvt_pk_fp8_f32(v, v, 0, false);
    *p = (u8)(pk & 0xff);
}

// C[M,Ncol] = A[M,K] @ Bt[Ncol,K]^T.  BK=64, XOR swizzle both sides (rule #21).
// FUSE: emits as_o/ad_o = per-row dots with att_s/att_d from fp32 accumulators.
template<int BM, int BN, typename TC, bool FUSE, int SWZ>
__global__ __launch_bounds__(256) void mgemm_k(const u16* __restrict__ A,
                                               const u16* __restrict__ Bt,
                                               TC* __restrict__ C,
                                               const float* __restrict__ att_s,
                                               const float* __restrict__ att_d,
                                               float* __restrict__ as_o,
                                               float* __restrict__ ad_o,
                                               int M, int K, int Ncol, int NH) {
    __shared__ __align__(16) u16 As[BM * 64];
    __shared__ __align__(16) u16 Bs[BN * 64];
    __shared__ float asL[2][BM], adL[2][BM];
    int tid = threadIdx.x;
    int wid = tid >> 6, lane = tid & 63;

    int wg = blockIdx.x;
    if (SWZ) { int q = gridDim.x >> 3; wg = (blockIdx.x & 7) * q + (blockIdx.x >> 3); }
    int nbn = Ncol / BN;
    int bm_i = wg / nbn, bn_i = wg % nbn;
    int bm = bm_i * BM, bn = bn_i * BN;

    constexpr int WN = BN / 2;
    constexpr int FM = 4;
    constexpr int FN = WN / 16;
    constexpr int TA = BM * 64 * 2 / 1024;
    constexpr int TB = BN * 64 * 2 / 1024;
    int wr = wid >> 1, wc = wid & 1;

    f32x4 acc[FM][FN] = {};

    for (int k0 = 0; k0 < K; k0 += 64) {
#pragma unroll
        for (int i = 0; i < TA / 4; ++i) {
            int t = wid * (TA / 4) + i;
            int o = t * 1024 + lane * 16;
            int m = o >> 7;
            int b = o & 127;
            int kb = b ^ ((m & 7) << 4);
            int gm = bm + m; if (gm >= M) gm = M - 1;
            gload_lds16(A + ((size_t)gm * K + k0 + (kb >> 1)), (char*)As + t * 1024);
        }
#pragma unroll
        for (int i = 0; i < TB / 4; ++i) {
            int t = wid * (TB / 4) + i;
            int o = t * 1024 + lane * 16;
            int n = o >> 7;
            int b = o & 127;
            int kb = b ^ ((n & 7) << 4);
            gload_lds16(Bt + ((size_t)(bn + n) * K + k0 + (kb >> 1)), (char*)Bs + t * 1024);
        }
        __syncthreads();
        int g = lane >> 4, r = lane & 15;
#pragma unroll
        for (int kh = 0; kh < 2; ++kh) {
            int kbb = g * 16 + kh * 64;
            bf16x8 af[FM], bfr[FN];
#pragma unroll
            for (int fm = 0; fm < FM; ++fm) {
                int m = wr * 64 + fm * 16 + r;
                af[fm] = *(const bf16x8*)((const char*)As + m * 128 + (kbb ^ ((m & 7) << 4)));
            }
#pragma unroll
            for (int fn = 0; fn < FN; ++fn) {
                int n = wc * WN + fn * 16 + r;
                bfr[fn] = *(const bf16x8*)((const char*)Bs + n * 128 + (kbb ^ ((n & 7) << 4)));
            }
#pragma unroll
            for (int fm = 0; fm < FM; ++fm)
#pragma unroll
                for (int fn = 0; fn < FN; ++fn)
                    acc[fm][fn] = __builtin_amdgcn_mfma_f32_16x16x32_bf16(af[fm], bfr[fn], acc[fm][fn], 0, 0, 0);
        }
        __syncthreads();
    }
    // C write: col = lane&15, row = (lane>>4)*4 + reg  (m89-verified)
#pragma unroll
    for (int fm = 0; fm < FM; ++fm)
#pragma unroll
        for (int fn = 0; fn < FN; ++fn)
#pragma unroll
            for (int rr = 0; rr < 4; ++rr) {
                int gm = bm + wr * 64 + fm * 16 + (lane >> 4) * 4 + rr;
                int gn = bn + wc * WN + fn * 16 + (lane & 15);
                if (gm < M) stf(&C[(size_t)gm * Ncol + gn], acc[fm][fn][rr]);
            }

    if constexpr (FUSE) {
        float asv[FN], adv[FN];
#pragma unroll
        for (int fn = 0; fn < FN; ++fn) {
            int c = bn + wc * WN + fn * 16 + (lane & 15);
            asv[fn] = att_s[c]; adv[fn] = att_d[c];
        }
#pragma unroll
        for (int fm = 0; fm < FM; ++fm)
#pragma unroll
            for (int rr = 0; rr < 4; ++rr) {
                float ps = 0.f, pd = 0.f;
#pragma unroll
                for (int fn = 0; fn < FN; ++fn) {
                    ps += acc[fm][fn][rr] * asv[fn];
                    pd += acc[fm][fn][rr] * adv[fn];
                }
#pragma unroll
                for (int off = 1; off < 16; off <<= 1) {
                    ps += __shfl_xor(ps, off);
                    pd += __shfl_xor(pd, off);
                }
                if ((lane & 15) == 0) {
                    int rl = wr * 64 + fm * 16 + (lane >> 4) * 4 + rr;
                    asL[wc][rl] = ps; adL[wc][rl] = pd;
                }
            }
        __syncthreads();
        if (tid < BM) {
            int gm = bm + tid;
            if (gm < M) {
                as_o[(size_t)gm * NH + bn_i] = asL[0][tid] + asL[1][tid];
                ad_o[(size_t)gm * NH + bn_i] = adL[0][tid] + adL[1][tid];
            }
        }
    }
}

// ---------------- layer-1 aggregation (fp8 gather, single-pass, persistent) ----------------
// persistent blocks stride over dst nodes. Per node, per 64-edge chunk:
// unnormalized alpha=exp(lrelu(.)) into LDS (z accumulated), then 4 edge-groups
// x 64 lanes x 16B fp8 gather with depth-2 prefetch. Final: z-reduce, scale,
// bias+ELU, non-temporal bf16 store.
__global__ __launch_bounds__(256) void agg1_k(const u8* __restrict__ h1,
                                              const float* __restrict__ as1,
                                              const float* __restrict__ ad1,
                                              const int* __restrict__ start,
                                              const int* __restrict__ cnt,
                                              const int* __restrict__ csr_src,
                                              const float* __restrict__ b1,
                                              u16* __restrict__ out1) {
    int tid = threadIdx.x;
    __shared__ float ad_sh[8], rz_sh[8];
    __shared__ int src_sh[64];
    __shared__ float al_sh[64][8];
    __shared__ float zred[256];
    __shared__ float comb[3][64][17];   // +1 pad: bank-conflict-free
    int l = tid & 63, grp = tid >> 6;
    int myh = l >> 3;                   // lane l owns channels 16l..16l+15, head l>>3
    const char* h1b = (const char*)h1;

    for (int n = blockIdx.x; n < NN; n += gridDim.x) {
        int s0 = start[n], deg = cnt[n];
        if (tid < 8) ad_sh[tid] = ad1[n * 8 + tid];
        __syncthreads();

        float acc[16] = {};
        float zacc = 0.f;               // this thread's entries all have head tid&7

        for (int e0 = 0; e0 < deg; e0 += 64) {
            int ne = min(64, deg - e0);
            if (tid < ne) src_sh[tid] = csr_src[s0 + e0 + tid];
            __syncthreads();
            for (int i = tid; i < ne * 8; i += 256) {
                int ee = i >> 3, hh = i & 7;
                int s = src_sh[ee];
                float al = __expf(lrelu(as1[s * 8 + hh] + ad_sh[hh]));
                al_sh[ee][hh] = al;
                zacc += al;
            }
            __syncthreads();
            int j = grp;
            if (j < ne) {
                u32x4 v0 = *(const u32x4*)(h1b + (size_t)src_sh[j] * 1024 + l * 16);
                int j1 = j + 4; bool b1v = j1 < ne;
                u32x4 v1;
                if (b1v) v1 = *(const u32x4*)(h1b + (size_t)src_sh[j1] * 1024 + l * 16);
                while (true) {
                    int j2 = j + 8; bool b2v = j2 < ne;
                    u32x4 v2;
                    if (b2v) v2 = *(const u32x4*)(h1b + (size_t)src_sh[j2] * 1024 + l * 16);
                    float al = al_sh[j][myh];
#pragma unroll
                    for (int w = 0; w < 4; ++w) {
                        u32 word = v0[w];
                        f32x2 p0 = __builtin_amdgcn_cvt_pk_f32_fp8(word, false);
                        f32x2 p1 = __builtin_amdgcn_cvt_pk_f32_fp8(word, true);
                        acc[w * 4 + 0] += al * p0.x;
                        acc[w * 4 + 1] += al * p0.y;
                        acc[w * 4 + 2] += al * p1.x;
                        acc[w * 4 + 3] += al * p1.y;
                    }
                    if (!b1v) break;
                    v0 = v1; j = j1;
                    v1 = v2; j1 = j2; b1v = b2v;
                }
            }
            __syncthreads();
        }

        // reduce z per head (thread tid's zacc belongs to head tid&7)
        zred[tid] = zacc;
        __syncthreads();
#pragma unroll
        for (int off = 128; off >= 8; off >>= 1) {
            if (tid < off) zred[tid] += zred[tid + off];
            __syncthreads();
        }
        if (tid < 8) rz_sh[tid] = 1.f / zred[tid];
        __syncthreads();

        if (grp) {
#pragma unroll
            for (int c = 0; c < 16; ++c) comb[grp - 1][l][c] = acc[c];
        }
        __syncthreads();
        if (!grp) {
            float rz = rz_sh[myh];
            int cbase = l * 16;
            float o[16];
#pragma unroll
            for (int c = 0; c < 16; ++c) {
                float zz = (acc[c] + comb[0][l][c] + comb[1][l][c] + comb[2][l][c]) * rz + b1[cbase + c];
                o[c] = zz > 0.f ? zz : (__expf(zz) - 1.f);
            }
            u32x4 pk0, pk1;
#pragma unroll
            for (int i = 0; i < 4; ++i) {
                pk0[i] = (u32)f2bs(o[2 * i])     | ((u32)f2bs(o[2 * i + 1]) << 16);
                pk1[i] = (u32)f2bs(o[8 + 2 * i]) | ((u32)f2bs(o[9 + 2 * i]) << 16);
            }
            char* dst = (char*)out1 + (size_t)n * 2048 + l * 32;
            __builtin_nontemporal_store(pk0, (u32x4*)dst);
            __builtin_nontemporal_store(pk1, (u32x4*)(dst + 16));
        }
        __syncthreads();
    }
}

// ---------------- layer-2 aggregation (single-pass, persistent) + log_softmax ----------------
// one wave per node, persistent; half-waves take alternating edges, depth-2 prefetch.
__global__ __launch_bounds__(256) void agg2_k(const u16* __restrict__ h2,
                                              const float* __restrict__ as2,
                                              const float* __restrict__ ad2,
                                              const int* __restrict__ start,
                                              const int* __restrict__ cnt,
                                              const int* __restrict__ csr_src,
                                              const float* __restrict__ b2,
                                              float* __restrict__ out) {
    int lane = threadIdx.x & 63;
    int wv = threadIdx.x >> 6;
    int half = lane >> 5, l = lane & 31;
    float b2a = b2[2 * l], b2b = b2[2 * l + 1];

    for (int n = blockIdx.x * 4 + wv; n < NN; n += gridDim.x * 4) {
        int s0 = start[n], deg = cnt[n];
        float adn = ad2[n];

        float a0 = 0.f, a1 = 0.f, z = 0.f;
        int j = half;
        bool bv0 = j < deg;
        if (bv0) {
            float e0v; u32 v0;
            {
                int s = csr_src[s0 + j];
                e0v = as2[s];
                v0 = *(const u32*)(h2 + (size_t)s * 64 + l * 2);
            }
            int j1 = j + 2; bool bv1 = j1 < deg;
            float e1v; u32 v1;
            if (bv1) {
                int s = csr_src[s0 + j1];
                e1v = as2[s];
                v1 = *(const u32*)(h2 + (size_t)s * 64 + l * 2);
            }
            while (true) {
                int j2 = j + 4; bool bv2 = j2 < deg;
                float e2v; u32 v2;
                if (bv2) {
                    int s = csr_src[s0 + j2];
                    e2v = as2[s];
                    v2 = *(const u32*)(h2 + (size_t)s * 64 + l * 2);
                }
                float al = __expf(lrelu(e0v + adn));
                z += al;
                a0 += al * us2f((u16)(v0 & 0xffff));
                a1 += al * us2f((u16)(v0 >> 16));
                if (!bv1) break;
                e0v = e1v; v0 = v1; j = j1;
                e1v = e2v; v1 = v2; j1 = j2; bv1 = bv2;
            }
        }
        a0 += __shfl_xor(a0, 32);
        a1 += __shfl_xor(a1, 32);
        z  += __shfl_xor(z, 32);
        float rz = 1.f / z;
        float y0 = a0 * rz + b2a, y1 = a1 * rz + b2b;

        // log_softmax over 64 channels (2 per lane, halves redundant)
        float mm = fmaxf(y0, y1);
#pragma unroll
        for (int off = 16; off; off >>= 1) mm = fmaxf(mm, __shfl_xor(mm, off));
        float se = __expf(y0 - mm) + __expf(y1 - mm);
#pragma unroll
        for (int off = 16; off; off >>= 1) se += __shfl_xor(se, off);
        float ls = __logf(se);
        if (half == 0) {
            float2 o; o.x = y0 - mm - ls; o.y = y1 - mm - ls;
            *(float2*)(out + (size_t)n * 64 + 2 * l) = o;
        }
    }
}

extern "C" void kernel_launch(void* const* d_in, const int* in_sizes, int n_in,
                              void* d_out, int out_size, void* d_ws, size_t ws_size,
                              hipStream_t stream) {
    const float* x     = (const float*)d_in[0];
    const int*   ei    = (const int*)d_in[1];
    const float* W1    = (const float*)d_in[2];
    const float* aw_s1 = (const float*)d_in[3];
    const float* aw_d1 = (const float*)d_in[4];
    const float* b1    = (const float*)d_in[5];
    const float* W2    = (const float*)d_in[6];
    const float* aw_s2 = (const float*)d_in[7];
    const float* aw_d2 = (const float*)d_in[8];
    const float* b2    = (const float*)d_in[9];
    float* out = (float*)d_out;

    char* ws = (char*)d_ws;
    size_t off = 0;
    auto alloc = [&](size_t bytes) -> void* {
        void* p = (void*)(ws + off);
        off += (bytes + 511) & ~(size_t)511;
        return p;
    };
    u16*   out1    = (u16*)alloc((size_t)NN * H1C * 2);   // aliases xb
    u16*   xb      = out1;
    u8*    h1      = (u8*)alloc((size_t)NN * H1C);        // fp8; aliases h2
    u16*   h2      = (u16*)h1;                            // bf16 6.4MB < 51.2MB
    u16*   w1t     = (u16*)alloc((size_t)H1C * INC * 2);
    u16*   w2t     = (u16*)alloc((size_t)OUTC * H1C * 2);
    float* as1     = (float*)alloc((size_t)NN * 8 * 4);
    float* ad1     = (float*)alloc((size_t)NN * 8 * 4);
    float* as2     = (float*)alloc((size_t)NN * 4);
    float* ad2     = (float*)alloc((size_t)NN * 4);
    int*   cnt     = (int*)alloc((size_t)NN * 4);         // cnt+cursor adjacent:
    int*   cursor  = (int*)alloc((size_t)NN * 4);         //   one fused memset
    int*   startp  = (int*)alloc((size_t)NN * 4);
    int*   csr_src = (int*)alloc((size_t)ET * 4);
    int    nsb     = (NN + 255) / 256;
    int*   bsum    = (int*)alloc((size_t)nsb * 4);
    int*   boff    = (int*)alloc((size_t)nsb * 4);

    if (off > ws_size) return;  // fail cleanly rather than OOB

    hipMemsetAsync(cnt, 0, (char*)(cursor + NN) - (char*)cnt, stream);

    // fused conversions + histogram
    int eblk = (ET + 255) / 256;
    cvtx_hist_k<<<CVTX_BLOCKS + eblk, 256, 0, stream>>>(x, xb, ei, cnt);
    cvt_w_k<<<(INC * H1C + OUTC * H1C) / 256, 256, 0, stream>>>(W1, w1t, W2, w2t);

    // CSR build
    scan1_k<<<nsb, 256, 0, stream>>>(cnt, startp, bsum);
    scan2_k<<<1, 256, 0, stream>>>(bsum, boff, nsb);
    scan3_k<<<nsb, 256, 0, stream>>>(startp, boff);
    scatter_k<<<eblk, 256, 0, stream>>>(ei, startp, cursor, csr_src);

    // layer 1: GEMM (fp8 C + fused alphas, XCD swizzle), persistent aggregation
    int nwg1 = (H1C / 128) * ((NN + 127) / 128);   // 3128, %8==0
    mgemm_k<128, 128, u8, true, 1><<<nwg1, 256, 0, stream>>>(
        xb, w1t, h1, aw_s1, aw_d1, as1, ad1, NN, INC, H1C, HEADS);
    agg1_k<<<4096, 256, 0, stream>>>(h1, as1, ad1, startp, cnt, csr_src, b1, out1);

    // layer 2
    int nwg2 = (OUTC / 64) * ((NN + 127) / 128);   // 391
    mgemm_k<128, 64, u16, true, 0><<<nwg2, 256, 0, stream>>>(
        out1, w2t, h2, aw_s2, aw_d2, as2, ad2, NN, H1C, OUTC, 1);
    agg2_k<<<1024, 256, 0, stream>>>(h2, as2, ad2, startp, cnt, csr_src, b2, out);
}

// Round 11
// 788.148 us; speedup vs baseline: 1.2645x; 1.2645x over previous
//
#include <hip/hip_runtime.h>
#include <hip/hip_bf16.h>

#define NN 50000
#define EE 1600000
#define ET (EE + NN)   // edges + self loops
#define HEADS 8
#define HID 128
#define INC 512
#define H1C (HEADS * HID)   // 1024
#define OUTC 64
#define NEG_SLOPE 0.2f

typedef unsigned short u16;
typedef unsigned int u32;
typedef unsigned char u8;
typedef __attribute__((ext_vector_type(8))) __bf16 bf16x8;
typedef __attribute__((ext_vector_type(4))) float f32x4;
typedef __attribute__((ext_vector_type(2))) float f32x2;
typedef __attribute__((ext_vector_type(4))) u32 u32x4;

__device__ __forceinline__ float lrelu(float x) { return x > 0.f ? x : NEG_SLOPE * x; }
__device__ __forceinline__ float us2f(u16 u) { return __uint_as_float(((u32)u) << 16); }
__device__ __forceinline__ u16 f2bs(float f) {
    u32 u = __float_as_uint(f);
    u += 0x7fffu + ((u >> 16) & 1u);
    return (u16)(u >> 16);
}

__device__ __forceinline__ void gload_lds16(const void* g, void* lds) {
    __builtin_amdgcn_global_load_lds((const __attribute__((address_space(1))) void*)g,
                                     (__attribute__((address_space(3))) void*)lds, 16, 0, 0);
}

// ---------------- fused: x->bf16 cast  +  degree histogram ----------------
#define CVTX_BLOCKS 25000   // NN*INC/4/256
__global__ __launch_bounds__(256) void cvtx_hist_k(const float* __restrict__ x, u16* __restrict__ xb,
                                                   const int* __restrict__ ei, int* __restrict__ cnt) {
    int b = blockIdx.x;
    if (b < CVTX_BLOCKS) {
        int i = b * 256 + threadIdx.x;
        float4 v = ((const float4*)x)[i];
        ushort4 o; o.x = f2bs(v.x); o.y = f2bs(v.y); o.z = f2bs(v.z); o.w = f2bs(v.w);
        ((ushort4*)xb)[i] = o;
    } else {
        int e = (b - CVTX_BLOCKS) * 256 + threadIdx.x;
        if (e < ET) {
            int d = (e < EE) ? ei[EE + e] : (e - EE);
            atomicAdd(&cnt[d], 1);
        }
    }
}

// ---------------- fused weight transposes (bf16) ----------------
__global__ __launch_bounds__(256) void cvt_w_k(const float* __restrict__ W1, u16* __restrict__ W1t,
                                               const float* __restrict__ W2, u16* __restrict__ W2t) {
    int idx = blockIdx.x * 256 + threadIdx.x;
    if (idx < INC * H1C) {               // W1t[n][k] = W1[k][n], 1024x512
        int n = idx >> 9, k = idx & 511;
        W1t[idx] = f2bs(W1[k * 1024 + n]);
    } else {                             // W2t[n][k] = W2[k][n], 64x1024
        int j = idx - INC * H1C;
        int n = j >> 10, k = j & 1023;
        W2t[j] = f2bs(W2[k * 64 + n]);
    }
}

// ---------------- hierarchical scan ----------------
__global__ __launch_bounds__(256) void scan1_k(const int* __restrict__ cnt,
                                               int* __restrict__ startp, int* __restrict__ bsum) {
    __shared__ int ws[8];
    int tid = threadIdx.x;
    int i = blockIdx.x * 256 + tid;
    int v = (i < NN) ? cnt[i] : 0;
    int lane = tid & 63, w = tid >> 6;
    int x = v;
#pragma unroll
    for (int off = 1; off < 64; off <<= 1) { int t = __shfl_up(x, off); if (lane >= off) x += t; }
    if (lane == 63) ws[w] = x;
    __syncthreads();
    if (tid == 0) { int s = 0; for (int k = 0; k < 4; ++k) { int t = ws[k]; ws[k] = s; s += t; } }
    __syncthreads();
    x += ws[w];
    if (i < NN) startp[i] = x - v;
    if (tid == 255) bsum[blockIdx.x] = x;
}

__global__ __launch_bounds__(256) void scan2_k(const int* __restrict__ bsum,
                                               int* __restrict__ boff, int nb) {
    __shared__ int ws[8];
    int tid = threadIdx.x;
    int v = (tid < nb) ? bsum[tid] : 0;
    int lane = tid & 63, w = tid >> 6;
    int x = v;
#pragma unroll
    for (int off = 1; off < 64; off <<= 1) { int t = __shfl_up(x, off); if (lane >= off) x += t; }
    if (lane == 63) ws[w] = x;
    __syncthreads();
    if (tid == 0) { int s = 0; for (int k = 0; k < 4; ++k) { int t = ws[k]; ws[k] = s; s += t; } }
    __syncthreads();
    x += ws[w];
    if (tid < nb) boff[tid] = x - v;
}

__global__ __launch_bounds__(256) void scan3_k(int* __restrict__ startp, const int* __restrict__ boff) {
    int i = blockIdx.x * 256 + threadIdx.x;
    if (i < NN) startp[i] += boff[blockIdx.x];
}

__global__ __launch_bounds__(256) void scatter_k(const int* __restrict__ ei,
                                                 const int* __restrict__ start,
                                                 int* __restrict__ cursor,
                                                 int* __restrict__ csr_src) {
    int e = blockIdx.x * 256 + threadIdx.x;
    if (e >= ET) return;
    int s, d;
    if (e < EE) { s = ei[e]; d = ei[EE + e]; }
    else        { s = e - EE; d = e - EE; }
    int pos = start[d] + atomicAdd(&cursor[d], 1);
    csr_src[pos] = s;
}

// ---------------- MFMA bf16 GEMM with fused alpha epilogue ----------------
__device__ __forceinline__ void stf(float* p, float v) { *p = v; }
__device__ __forceinline__ void stf(u16* p, float v)   { *p = f2bs(v); }
__device__ __forceinline__ void stf(u8* p, float v) {   // fp8 e4m3 (OCP), RTNE
    u32 pk = __builtin_amdgcn_cvt_pk_fp8_f32(v, v, 0, false);
    *p = (u8)(pk & 0xff);
}

// C[M,Ncol] = A[M,K] @ Bt[Ncol,K]^T.  BK=64, XOR swizzle both sides (rule #21).
// FUSE: emits as_o/ad_o = per-row dots with att_s/att_d from fp32 accumulators.
template<int BM, int BN, typename TC, bool FUSE, int SWZ>
__global__ __launch_bounds__(256) void mgemm_k(const u16* __restrict__ A,
                                               const u16* __restrict__ Bt,
                                               TC* __restrict__ C,
                                               const float* __restrict__ att_s,
                                               const float* __restrict__ att_d,
                                               float* __restrict__ as_o,
                                               float* __restrict__ ad_o,
                                               int M, int K, int Ncol, int NH) {
    __shared__ __align__(16) u16 As[BM * 64];
    __shared__ __align__(16) u16 Bs[BN * 64];
    __shared__ float asL[2][BM], adL[2][BM];
    int tid = threadIdx.x;
    int wid = tid >> 6, lane = tid & 63;

    int wg = blockIdx.x;
    if (SWZ) { int q = gridDim.x >> 3; wg = (blockIdx.x & 7) * q + (blockIdx.x >> 3); }
    int nbn = Ncol / BN;
    int bm_i = wg / nbn, bn_i = wg % nbn;
    int bm = bm_i * BM, bn = bn_i * BN;

    constexpr int WN = BN / 2;
    constexpr int FM = 4;
    constexpr int FN = WN / 16;
    constexpr int TA = BM * 64 * 2 / 1024;
    constexpr int TB = BN * 64 * 2 / 1024;
    int wr = wid >> 1, wc = wid & 1;

    f32x4 acc[FM][FN] = {};

    for (int k0 = 0; k0 < K; k0 += 64) {
#pragma unroll
        for (int i = 0; i < TA / 4; ++i) {
            int t = wid * (TA / 4) + i;
            int o = t * 1024 + lane * 16;
            int m = o >> 7;
            int b = o & 127;
            int kb = b ^ ((m & 7) << 4);
            int gm = bm + m; if (gm >= M) gm = M - 1;
            gload_lds16(A + ((size_t)gm * K + k0 + (kb >> 1)), (char*)As + t * 1024);
        }
#pragma unroll
        for (int i = 0; i < TB / 4; ++i) {
            int t = wid * (TB / 4) + i;
            int o = t * 1024 + lane * 16;
            int n = o >> 7;
            int b = o & 127;
            int kb = b ^ ((n & 7) << 4);
            gload_lds16(Bt + ((size_t)(bn + n) * K + k0 + (kb >> 1)), (char*)Bs + t * 1024);
        }
        __syncthreads();
        int g = lane >> 4, r = lane & 15;
#pragma unroll
        for (int kh = 0; kh < 2; ++kh) {
            int kbb = g * 16 + kh * 64;
            bf16x8 af[FM], bfr[FN];
#pragma unroll
            for (int fm = 0; fm < FM; ++fm) {
                int m = wr * 64 + fm * 16 + r;
                af[fm] = *(const bf16x8*)((const char*)As + m * 128 + (kbb ^ ((m & 7) << 4)));
            }
#pragma unroll
            for (int fn = 0; fn < FN; ++fn) {
                int n = wc * WN + fn * 16 + r;
                bfr[fn] = *(const bf16x8*)((const char*)Bs + n * 128 + (kbb ^ ((n & 7) << 4)));
            }
#pragma unroll
            for (int fm = 0; fm < FM; ++fm)
#pragma unroll
                for (int fn = 0; fn < FN; ++fn)
                    acc[fm][fn] = __builtin_amdgcn_mfma_f32_16x16x32_bf16(af[fm], bfr[fn], acc[fm][fn], 0, 0, 0);
        }
        __syncthreads();
    }
    // C write: col = lane&15, row = (lane>>4)*4 + reg  (m89-verified)
#pragma unroll
    for (int fm = 0; fm < FM; ++fm)
#pragma unroll
        for (int fn = 0; fn < FN; ++fn)
#pragma unroll
            for (int rr = 0; rr < 4; ++rr) {
                int gm = bm + wr * 64 + fm * 16 + (lane >> 4) * 4 + rr;
                int gn = bn + wc * WN + fn * 16 + (lane & 15);
                if (gm < M) stf(&C[(size_t)gm * Ncol + gn], acc[fm][fn][rr]);
            }

    if constexpr (FUSE) {
        float asv[FN], adv[FN];
#pragma unroll
        for (int fn = 0; fn < FN; ++fn) {
            int c = bn + wc * WN + fn * 16 + (lane & 15);
            asv[fn] = att_s[c]; adv[fn] = att_d[c];
        }
#pragma unroll
        for (int fm = 0; fm < FM; ++fm)
#pragma unroll
            for (int rr = 0; rr < 4; ++rr) {
                float ps = 0.f, pd = 0.f;
#pragma unroll
                for (int fn = 0; fn < FN; ++fn) {
                    ps += acc[fm][fn][rr] * asv[fn];
                    pd += acc[fm][fn][rr] * adv[fn];
                }
#pragma unroll
                for (int off = 1; off < 16; off <<= 1) {
                    ps += __shfl_xor(ps, off);
                    pd += __shfl_xor(pd, off);
                }
                if ((lane & 15) == 0) {
                    int rl = wr * 64 + fm * 16 + (lane >> 4) * 4 + rr;
                    asL[wc][rl] = ps; adL[wc][rl] = pd;
                }
            }
        __syncthreads();
        if (tid < BM) {
            int gm = bm + tid;
            if (gm < M) {
                as_o[(size_t)gm * NH + bn_i] = asL[0][tid] + asL[1][tid];
                ad_o[(size_t)gm * NH + bn_i] = adL[0][tid] + adL[1][tid];
            }
        }
    }
}

// ---------------- layer-1 aggregation (fp8 gather, single-pass no-max softmax) ----------------
// one block per dst node (round-9 structure verbatim: occupancy is the
// latency-hiding resource here; persistent/deep-prefetch variants regress).
__global__ __launch_bounds__(256) void agg1_k(const u8* __restrict__ h1,
                                              const float* __restrict__ as1,
                                              const float* __restrict__ ad1,
                                              const int* __restrict__ start,
                                              const int* __restrict__ cnt,
                                              const int* __restrict__ csr_src,
                                              const float* __restrict__ b1,
                                              u16* __restrict__ out1) {
    int n = blockIdx.x;
    int tid = threadIdx.x;
    int s0 = start[n], deg = cnt[n];
    __shared__ float ad_sh[8], rz_sh[8];
    __shared__ int src_sh[64];
    __shared__ float al_sh[64][8];
    __shared__ float zred[256];
    __shared__ float comb[3][64][17];   // +1 pad: bank-conflict-free

    if (tid < 8) ad_sh[tid] = ad1[n * 8 + tid];
    __syncthreads();

    int l = tid & 63, grp = tid >> 6;
    int myh = l >> 3;                    // lane l owns channels 16l..16l+15, head l>>3
    float acc[16] = {};
    float zacc = 0.f;                    // this thread's entries all have head tid&7
    const char* h1b = (const char*)h1;

    for (int e0 = 0; e0 < deg; e0 += 64) {
        int ne = min(64, deg - e0);
        if (tid < ne) src_sh[tid] = csr_src[s0 + e0 + tid];
        __syncthreads();
        // unnormalized alphas for this chunk (stride 256 ≡ 0 mod 8 -> fixed head/thread)
        for (int i = tid; i < ne * 8; i += 256) {
            int ee = i >> 3, hh = i & 7;
            int s = src_sh[ee];
            float al = __expf(lrelu(as1[s * 8 + hh] + ad_sh[hh]));
            al_sh[ee][hh] = al;
            zacc += al;
        }
        __syncthreads();
        int j = grp;
        if (j < ne) {
            u32x4 v = *(const u32x4*)(h1b + (size_t)src_sh[j] * 1024 + l * 16);
            while (true) {
                int jn = j + 4;
                bool more = jn < ne;
                u32x4 vn;
                if (more) vn = *(const u32x4*)(h1b + (size_t)src_sh[jn] * 1024 + l * 16);
                float al = al_sh[j][myh];
#pragma unroll
                for (int w = 0; w < 4; ++w) {
                    u32 word = v[w];
                    f32x2 p0 = __builtin_amdgcn_cvt_pk_f32_fp8(word, false);
                    f32x2 p1 = __builtin_amdgcn_cvt_pk_f32_fp8(word, true);
                    acc[w * 4 + 0] += al * p0.x;
                    acc[w * 4 + 1] += al * p0.y;
                    acc[w * 4 + 2] += al * p1.x;
                    acc[w * 4 + 3] += al * p1.y;
                }
                if (!more) break;
                v = vn; j = jn;
            }
        }
        __syncthreads();
    }

    // reduce z per head (thread tid's zacc belongs to head tid&7)
    zred[tid] = zacc;
    __syncthreads();
#pragma unroll
    for (int off = 128; off >= 8; off >>= 1) {
        if (tid < off) zred[tid] += zred[tid + off];
        __syncthreads();
    }
    if (tid < 8) rz_sh[tid] = 1.f / zred[tid];
    __syncthreads();

    if (grp) {
#pragma unroll
        for (int c = 0; c < 16; ++c) comb[grp - 1][l][c] = acc[c];
    }
    __syncthreads();
    if (!grp) {
        float rz = rz_sh[myh];
        int cbase = l * 16;
        float o[16];
#pragma unroll
        for (int c = 0; c < 16; ++c) {
            float zz = (acc[c] + comb[0][l][c] + comb[1][l][c] + comb[2][l][c]) * rz + b1[cbase + c];
            o[c] = zz > 0.f ? zz : (__expf(zz) - 1.f);
        }
        u32x4 pk0, pk1;
#pragma unroll
        for (int i = 0; i < 4; ++i) {
            pk0[i] = (u32)f2bs(o[2 * i])     | ((u32)f2bs(o[2 * i + 1]) << 16);
            pk1[i] = (u32)f2bs(o[8 + 2 * i]) | ((u32)f2bs(o[9 + 2 * i]) << 16);
        }
        char* dst = (char*)out1 + (size_t)n * 2048 + l * 32;
        __builtin_nontemporal_store(pk0, (u32x4*)dst);
        __builtin_nontemporal_store(pk1, (u32x4*)(dst + 16));
    }
}

// ---------------- layer-2 aggregation (single-pass) + log_softmax: one wave per node ----------------
__global__ __launch_bounds__(256) void agg2_k(const u16* __restrict__ h2,
                                              const float* __restrict__ as2,
                                              const float* __restrict__ ad2,
                                              const int* __restrict__ start,
                                              const int* __restrict__ cnt,
                                              const int* __restrict__ csr_src,
                                              const float* __restrict__ b2,
                                              float* __restrict__ out) {
    int n = blockIdx.x * 4 + (threadIdx.x >> 6);
    int lane = threadIdx.x & 63;
    if (n >= NN) return;
    int s0 = start[n], deg = cnt[n];
    float adn = ad2[n];

    // single pass: half-waves take alternating edges, u32 (2ch)/lane, prefetch;
    // unnormalized alpha (no-max softmax), z accumulated (identical across a half's lanes)
    int half = lane >> 5, l = lane & 31;
    float a0 = 0.f, a1 = 0.f, z = 0.f;
    int j = half;
    if (j < deg) {
        int s = csr_src[s0 + j];
        float asv = as2[s];
        u32 v = *(const u32*)(h2 + (size_t)s * 64 + l * 2);
        while (true) {
            int jn = j + 2;
            bool more = jn < deg;
            int sn; float asn; u32 vn;
            if (more) {
                sn = csr_src[s0 + jn];
                asn = as2[sn];
                vn = *(const u32*)(h2 + (size_t)sn * 64 + l * 2);
            }
            float al = __expf(lrelu(asv + adn));
            z += al;
            a0 += al * us2f((u16)(v & 0xffff));
            a1 += al * us2f((u16)(v >> 16));
            if (!more) break;
            asv = asn; v = vn; j = jn;
        }
    }
    a0 += __shfl_xor(a0, 32);
    a1 += __shfl_xor(a1, 32);
    z  += __shfl_xor(z, 32);
    float rz = 1.f / z;
    float y0 = a0 * rz + b2[2 * l], y1 = a1 * rz + b2[2 * l + 1];

    // log_softmax over 64 channels (2 per lane, halves redundant)
    float mm = fmaxf(y0, y1);
#pragma unroll
    for (int off = 16; off; off >>= 1) mm = fmaxf(mm, __shfl_xor(mm, off));
    float se = __expf(y0 - mm) + __expf(y1 - mm);
#pragma unroll
    for (int off = 16; off; off >>= 1) se += __shfl_xor(se, off);
    float ls = __logf(se);
    if (half == 0) {
        float2 o; o.x = y0 - mm - ls; o.y = y1 - mm - ls;
        *(float2*)(out + (size_t)n * 64 + 2 * l) = o;
    }
}

extern "C" void kernel_launch(void* const* d_in, const int* in_sizes, int n_in,
                              void* d_out, int out_size, void* d_ws, size_t ws_size,
                              hipStream_t stream) {
    const float* x     = (const float*)d_in[0];
    const int*   ei    = (const int*)d_in[1];
    const float* W1    = (const float*)d_in[2];
    const float* aw_s1 = (const float*)d_in[3];
    const float* aw_d1 = (const float*)d_in[4];
    const float* b1    = (const float*)d_in[5];
    const float* W2    = (const float*)d_in[6];
    const float* aw_s2 = (const float*)d_in[7];
    const float* aw_d2 = (const float*)d_in[8];
    const float* b2    = (const float*)d_in[9];
    float* out = (float*)d_out;

    char* ws = (char*)d_ws;
    size_t off = 0;
    auto alloc = [&](size_t bytes) -> void* {
        void* p = (void*)(ws + off);
        off += (bytes + 511) & ~(size_t)511;
        return p;
    };
    u16*   out1    = (u16*)alloc((size_t)NN * H1C * 2);   // aliases xb
    u16*   xb      = out1;
    u8*    h1      = (u8*)alloc((size_t)NN * H1C);        // fp8; aliases h2
    u16*   h2      = (u16*)h1;                            // bf16 6.4MB < 51.2MB
    u16*   w1t     = (u16*)alloc((size_t)H1C * INC * 2);
    u16*   w2t     = (u16*)alloc((size_t)OUTC * H1C * 2);
    float* as1     = (float*)alloc((size_t)NN * 8 * 4);
    float* ad1     = (float*)alloc((size_t)NN * 8 * 4);
    float* as2     = (float*)alloc((size_t)NN * 4);
    float* ad2     = (float*)alloc((size_t)NN * 4);
    int*   cnt     = (int*)alloc((size_t)NN * 4);         // cnt+cursor adjacent:
    int*   cursor  = (int*)alloc((size_t)NN * 4);         //   one fused memset
    int*   startp  = (int*)alloc((size_t)NN * 4);
    int*   csr_src = (int*)alloc((size_t)ET * 4);
    int    nsb     = (NN + 255) / 256;
    int*   bsum    = (int*)alloc((size_t)nsb * 4);
    int*   boff    = (int*)alloc((size_t)nsb * 4);

    if (off > ws_size) return;  // fail cleanly rather than OOB

    hipMemsetAsync(cnt, 0, (char*)(cursor + NN) - (char*)cnt, stream);

    // fused conversions + histogram
    int eblk = (ET + 255) / 256;
    cvtx_hist_k<<<CVTX_BLOCKS + eblk, 256, 0, stream>>>(x, xb, ei, cnt);
    cvt_w_k<<<(INC * H1C + OUTC * H1C) / 256, 256, 0, stream>>>(W1, w1t, W2, w2t);

    // CSR build
    scan1_k<<<nsb, 256, 0, stream>>>(cnt, startp, bsum);
    scan2_k<<<1, 256, 0, stream>>>(bsum, boff, nsb);
    scan3_k<<<nsb, 256, 0, stream>>>(startp, boff);
    scatter_k<<<eblk, 256, 0, stream>>>(ei, startp, cursor, csr_src);

    // layer 1: GEMM (fp8 C + fused alphas, XCD swizzle), aggregation
    int nwg1 = (H1C / 128) * ((NN + 127) / 128);   // 3128, %8==0
    mgemm_k<128, 128, u8, true, 1><<<nwg1, 256, 0, stream>>>(
        xb, w1t, h1, aw_s1, aw_d1, as1, ad1, NN, INC, H1C, HEADS);
    agg1_k<<<NN, 256, 0, stream>>>(h1, as1, ad1, startp, cnt, csr_src, b1, out1);

    // layer 2
    int nwg2 = (OUTC / 64) * ((NN + 127) / 128);   // 391
    mgemm_k<128, 64, u16, true, 0><<<nwg2, 256, 0, stream>>>(
        out1, w2t, h2, aw_s2, aw_d2, as2, ad2, NN, H1C, OUTC, 1);
    agg2_k<<<(NN + 3) / 4, 256, 0, stream>>>(h2, as2, ad2, startp, cnt, csr_src, b2, out);
}